// Round 12
// baseline (178.094 us; speedup 1.0000x reference)
//
#include <hip/hip_runtime.h>
#include <hip/hip_bf16.h>

// fp32 inputs (confirmed r2). Internal pipeline bf16 MFMA.
// Gen identity: w = exp2(max(e,0.2e)) = max(A_i*B_j, C_i*D_j).
// r12 = r11 with ONE change: prefetch distance 2 (tile k+2 loaded post-barrier
//   of iter k into slot k&1, freed by store V(k) at iter top). Loads are ~2
//   iterations old at consumption -> L2 latency hidden at store AND gen.

typedef unsigned short ushort_t;
typedef __attribute__((ext_vector_type(8))) short bf16x8;
typedef __attribute__((ext_vector_type(4))) float f32x4;

#define LOG2E 1.4426950408889634f

__device__ __forceinline__ ushort_t f2bf(float x) {
    unsigned u = __builtin_bit_cast(unsigned, x);
    u += 0x7FFFu + ((u >> 16) & 1u);   // RNE
    return (ushort_t)(u >> 16);
}

// ---------------- kernel 0: pack adj (int32 0/1) -> bitmask (r9 proven) ----------
__global__ __launch_bounds__(256) void pack_adj(const int* __restrict__ adj,
                                                unsigned char* __restrict__ pk) {
    int wv = threadIdx.x >> 6, lane = threadIdx.x & 63;
    int row = blockIdx.x * 4 + wv;
    const int* ap = adj + (unsigned)row * 4096 + lane;
    unsigned char* pp = pk + (unsigned)row * 512;
    int jo = lane & 7;
#pragma unroll 2
    for (int k4 = 0; k4 < 16; k4++) {
        int v0 = ap[(k4 * 4 + 0) * 64];
        int v1 = ap[(k4 * 4 + 1) * 64];
        int v2 = ap[(k4 * 4 + 2) * 64];
        int v3 = ap[(k4 * 4 + 3) * 64];
        unsigned long long m0 = __ballot(v0 > 0);
        unsigned long long m1 = __ballot(v1 > 0);
        unsigned long long m2 = __ballot(v2 > 0);
        unsigned long long m3 = __ballot(v3 > 0);
        if (lane < 8) {
            int sh = jo * 8;
            unsigned b = ((unsigned)(m0 >> sh) & 0xFFu)
                       | (((unsigned)(m1 >> sh) & 0xFFu) << 8)
                       | (((unsigned)(m2 >> sh) & 0xFFu) << 16)
                       | (((unsigned)(m3 >> sh) & 0xFFu) << 24);
            *(unsigned*)(pp + jo * 64 + k4 * 4) = b;
        }
    }
}

// ---------------- kernel 1: WT[c][k] = W[k][c], 512x512, fp32 -> bf16 ----------------
__global__ __launch_bounds__(256) void transpose_w(const float* __restrict__ W,
                                                   ushort_t* __restrict__ WT) {
    __shared__ ushort_t t[32][33];
    int bx = blockIdx.x & 15, by = blockIdx.x >> 4;
    int tx = threadIdx.x & 31, ty = threadIdx.x >> 5;
#pragma unroll
    for (int i = 0; i < 32; i += 8)
        t[ty + i][tx] = f2bf(W[(by * 32 + ty + i) * 512 + bx * 32 + tx]);
    __syncthreads();
#pragma unroll
    for (int i = 0; i < 32; i += 8)
        WT[(bx * 32 + ty + i) * 512 + by * 32 + tx] = t[tx][ty + i];
}

// -------- kernel 2: WhT = WT @ h^T, pipelined (r8 proven) + exp epilogue --------
__global__ __launch_bounds__(256, 4) void gemm_whT(const ushort_t* __restrict__ WT,
                                                   const float* __restrict__ h,
                                                   const float* __restrict__ a,
                                                   ushort_t* __restrict__ WhT,
                                                   float* __restrict__ expA,
                                                   float* __restrict__ expC,
                                                   float* __restrict__ expB,
                                                   float* __restrict__ expD) {
    __shared__ __align__(16) ushort_t Al[2][64][72];
    __shared__ __align__(16) ushort_t Bl[2][64][72];
    __shared__ float asrc[64], adst[64];
    __shared__ float sred[2][4][64];
    int tid = threadIdx.x;
    int wave = tid >> 6, lane = tid & 63, quad = lane >> 4, nn = lane & 15;
    int mb = blockIdx.x & 7, nb = blockIdx.x >> 3;
    if (tid < 64) {
        asrc[tid] = a[tid] * LOG2E;
        adst[tid] = a[64 + tid] * LOG2E;
    }
    int r = tid >> 2, s0 = tid & 3;
    const ushort_t* Ag = WT + (unsigned)((mb * 64 + r) * 512 + s0 * 8);
    const float* Bg = h + (unsigned)((nb * 64 + r) * 512 + s0 * 8);
    bf16x8 pA0 = *(const bf16x8*)(Ag);
    bf16x8 pA1 = *(const bf16x8*)(Ag + 32);
    float4 pb0 = *(const float4*)(Bg);
    float4 pb1 = *(const float4*)(Bg + 4);
    float4 pb2 = *(const float4*)(Bg + 32);
    float4 pb3 = *(const float4*)(Bg + 36);
    f32x4 acc[4] = {};
#pragma unroll 2
    for (int t = 0; t < 8; t++) {
        int cb = t & 1;
        *(bf16x8*)&Al[cb][r][s0 * 8] = pA0;
        *(bf16x8*)&Al[cb][r][s0 * 8 + 32] = pA1;
        bf16x8 bv;
        bv[0] = (short)f2bf(pb0.x); bv[1] = (short)f2bf(pb0.y);
        bv[2] = (short)f2bf(pb0.z); bv[3] = (short)f2bf(pb0.w);
        bv[4] = (short)f2bf(pb1.x); bv[5] = (short)f2bf(pb1.y);
        bv[6] = (short)f2bf(pb1.z); bv[7] = (short)f2bf(pb1.w);
        *(bf16x8*)&Bl[cb][r][s0 * 8] = bv;
        bv[0] = (short)f2bf(pb2.x); bv[1] = (short)f2bf(pb2.y);
        bv[2] = (short)f2bf(pb2.z); bv[3] = (short)f2bf(pb2.w);
        bv[4] = (short)f2bf(pb3.x); bv[5] = (short)f2bf(pb3.y);
        bv[6] = (short)f2bf(pb3.z); bv[7] = (short)f2bf(pb3.w);
        *(bf16x8*)&Bl[cb][r][s0 * 8 + 32] = bv;
        if (t < 7) {
            int ko = (t + 1) * 64;
            pA0 = *(const bf16x8*)(Ag + ko);
            pA1 = *(const bf16x8*)(Ag + ko + 32);
            pb0 = *(const float4*)(Bg + ko);
            pb1 = *(const float4*)(Bg + ko + 4);
            pb2 = *(const float4*)(Bg + ko + 32);
            pb3 = *(const float4*)(Bg + ko + 36);
        }
        if (t > 0) {
            int pb = cb ^ 1;
            bf16x8 af0 = *(const bf16x8*)&Al[pb][wave * 16 + nn][quad * 8];
            bf16x8 af1 = *(const bf16x8*)&Al[pb][wave * 16 + nn][32 + quad * 8];
#pragma unroll
            for (int nt = 0; nt < 4; nt++) {
                bf16x8 b0 = *(const bf16x8*)&Bl[pb][nt * 16 + nn][quad * 8];
                bf16x8 b1 = *(const bf16x8*)&Bl[pb][nt * 16 + nn][32 + quad * 8];
                acc[nt] = __builtin_amdgcn_mfma_f32_16x16x32_bf16(af0, b0, acc[nt], 0, 0, 0);
                acc[nt] = __builtin_amdgcn_mfma_f32_16x16x32_bf16(af1, b1, acc[nt], 0, 0, 0);
            }
        }
        __syncthreads();
    }
    {
        bf16x8 af0 = *(const bf16x8*)&Al[1][wave * 16 + nn][quad * 8];
        bf16x8 af1 = *(const bf16x8*)&Al[1][wave * 16 + nn][32 + quad * 8];
#pragma unroll
        for (int nt = 0; nt < 4; nt++) {
            bf16x8 b0 = *(const bf16x8*)&Bl[1][nt * 16 + nn][quad * 8];
            bf16x8 b1 = *(const bf16x8*)&Bl[1][nt * 16 + nn][32 + quad * 8];
            acc[nt] = __builtin_amdgcn_mfma_f32_16x16x32_bf16(af0, b0, acc[nt], 0, 0, 0);
            acc[nt] = __builtin_amdgcn_mfma_f32_16x16x32_bf16(af1, b1, acc[nt], 0, 0, 0);
        }
    }
    int row0 = mb * 64 + wave * 16 + quad * 4;
    int col0 = nb * 64 + nn;
    int f0i = wave * 16 + quad * 4;
#pragma unroll
    for (int nt = 0; nt < 4; nt++) {
        float s = 0.f, d = 0.f;
#pragma unroll
        for (int rr = 0; rr < 4; rr++) {
            float v = acc[nt][rr];
            WhT[(unsigned)((row0 + rr) * 4096 + col0 + nt * 16)] = f2bf(v);
            s += v * asrc[f0i + rr];
            d += v * adst[f0i + rr];
        }
        s += __shfl_xor(s, 16); s += __shfl_xor(s, 32);
        d += __shfl_xor(d, 16); d += __shfl_xor(d, 32);
        if (quad == 0) { sred[0][wave][nt * 16 + nn] = s; sred[1][wave][nt * 16 + nn] = d; }
    }
    __syncthreads();
    if (tid < 64) {
        float s = sred[0][0][tid] + sred[0][1][tid] + sred[0][2][tid] + sred[0][3][tid];
        unsigned idx = mb * 4096 + nb * 64 + tid;
        expA[idx] = __builtin_amdgcn_exp2f(s);
        expC[idx] = __builtin_amdgcn_exp2f(0.2f * s);
    } else if (tid < 128) {
        int c = tid - 64;
        float d = sred[1][0][c] + sred[1][1][c] + sred[1][2][c] + sred[1][3][c];
        unsigned idx = mb * 4096 + nb * 64 + c;
        expB[idx] = __builtin_amdgcn_exp2f(d);
        expD[idx] = __builtin_amdgcn_exp2f(0.2f * d);
    }
}

// -------- kernel 3: fused attention, identity mapping, distance-2 prefetch --------
// 512 blocks x 512 thr (512,4). Per iter k: store V(k) [slot k&1 freed];
// gen(k); BARRIER; [sched fence] load tile k+2 into slot k&1; MFMA(k).
__global__ __launch_bounds__(512, 4) void gat_attn(const unsigned char* __restrict__ pk,
                                                   const ushort_t* __restrict__ WhT,
                                                   const float* __restrict__ expA,
                                                   const float* __restrict__ expC,
                                                   const float* __restrict__ expB,
                                                   const float* __restrict__ expD,
                                                   float* __restrict__ out) {
    __shared__ __align__(16) ushort_t Vb[2][128][72];   // 36864 B (cmb overlays Vb[0])
    __shared__ float denomp[2][2][32];
    int tid = threadIdx.x;
    int wave = tid >> 6, lane = tid & 63, quad = lane >> 4, nn = lane & 15;
    int hb = blockIdx.x >> 7, ib = blockIdx.x & 127;   // adj row-band on one XCD
    int i0 = ib * 32;
    // identity mapping: this thread's gen == its MFMA A-fragment
    int jhalf = wave >> 2, ws = wave & 3;
    int whead = ws >> 1, strip = ws & 1;
    int pi = strip * 16 + nn, jo = jhalf * 4 + quad;
    int head = hb * 2 + whead;
    float Ai = expA[head * 4096 + i0 + pi];
    float Ci = expC[head * 4096 + i0 + pi];
    const unsigned char* mp = pk + (unsigned)(i0 + pi) * 512 + jo * 64;
    const float* Bp = expB + (unsigned)head * 4096 + jo * 8;
    const float* Dp = expD + (unsigned)head * 4096 + jo * 8;
    // V staging role (coalesced): rows vr, vr+64; 16B col-seg vcs
    int vr = tid >> 3, vcs = tid & 7;
    const ushort_t* Vg0 = WhT + (unsigned)(hb * 128 + vr) * 4096 + vcs * 8;
    const ushort_t* Vg1 = Vg0 + 64u * 4096u;
    bf16x8 onef;
#pragma unroll
    for (int i = 0; i < 8; i++) onef[i] = (short)0x3F80;   // bf16 1.0
    f32x4 acc[4] = {};
    f32x4 accd = {};
    // prologue: prefetch tiles 0 and 1 (distance-2 pipeline)
    bf16x8 pv[2][2];
    float4 pBD[2][4];
    pv[0][0] = *(const bf16x8*)(Vg0);
    pv[0][1] = *(const bf16x8*)(Vg1);
    pv[1][0] = *(const bf16x8*)(Vg0 + 64);
    pv[1][1] = *(const bf16x8*)(Vg1 + 64);
    pBD[0][0] = *(const float4*)(Bp);
    pBD[0][1] = *(const float4*)(Bp + 4);
    pBD[0][2] = *(const float4*)(Dp);
    pBD[0][3] = *(const float4*)(Dp + 4);
    pBD[1][0] = *(const float4*)(Bp + 64);
    pBD[1][1] = *(const float4*)(Bp + 68);
    pBD[1][2] = *(const float4*)(Dp + 64);
    pBD[1][3] = *(const float4*)(Dp + 68);
    unsigned mcur = *(const unsigned*)(mp);
    unsigned mnext = 0;
    for (int t = 0; t < 16; t++) {
#pragma unroll
        for (int u = 0; u < 4; u++) {
            int k = t * 4 + u;
            int cb = k & 1;
            // ---- store V tile k (frees slot cb) ----
            *(bf16x8*)&Vb[cb][vr][vcs * 8] = pv[cb][0];
            *(bf16x8*)&Vb[cb][64 + vr][vcs * 8] = pv[cb][1];
            // ---- gen tile k: own A-fragment in registers ----
            float4 Bv0 = pBD[cb][0], Bv1 = pBD[cb][1];
            float4 Dv0 = pBD[cb][2], Dv1 = pBD[cb][3];
            unsigned w0, w1, w2, w3, w4, w5, w6, w7;
            {
                float w;
                w = fmaxf(Ai * Bv0.x, Ci * Dv0.x);
                w0 = __builtin_bit_cast(unsigned, w) & 0xFFFF0000u;
                w0 &= (unsigned)__builtin_amdgcn_sbfe(mcur, u * 8 + 0, 1);
                w = fmaxf(Ai * Bv0.y, Ci * Dv0.y);
                w1 = __builtin_bit_cast(unsigned, w) & 0xFFFF0000u;
                w1 &= (unsigned)__builtin_amdgcn_sbfe(mcur, u * 8 + 1, 1);
                w = fmaxf(Ai * Bv0.z, Ci * Dv0.z);
                w2 = __builtin_bit_cast(unsigned, w) & 0xFFFF0000u;
                w2 &= (unsigned)__builtin_amdgcn_sbfe(mcur, u * 8 + 2, 1);
                w = fmaxf(Ai * Bv0.w, Ci * Dv0.w);
                w3 = __builtin_bit_cast(unsigned, w) & 0xFFFF0000u;
                w3 &= (unsigned)__builtin_amdgcn_sbfe(mcur, u * 8 + 3, 1);
                w = fmaxf(Ai * Bv1.x, Ci * Dv1.x);
                w4 = __builtin_bit_cast(unsigned, w) & 0xFFFF0000u;
                w4 &= (unsigned)__builtin_amdgcn_sbfe(mcur, u * 8 + 4, 1);
                w = fmaxf(Ai * Bv1.y, Ci * Dv1.y);
                w5 = __builtin_bit_cast(unsigned, w) & 0xFFFF0000u;
                w5 &= (unsigned)__builtin_amdgcn_sbfe(mcur, u * 8 + 5, 1);
                w = fmaxf(Ai * Bv1.z, Ci * Dv1.z);
                w6 = __builtin_bit_cast(unsigned, w) & 0xFFFF0000u;
                w6 &= (unsigned)__builtin_amdgcn_sbfe(mcur, u * 8 + 6, 1);
                w = fmaxf(Ai * Bv1.w, Ci * Dv1.w);
                w7 = __builtin_bit_cast(unsigned, w) & 0xFFFF0000u;
                w7 &= (unsigned)__builtin_amdgcn_sbfe(mcur, u * 8 + 7, 1);
            }
            uint4 pq;
            pq.x = __builtin_amdgcn_perm(w1, w0, 0x07060302u);
            pq.y = __builtin_amdgcn_perm(w3, w2, 0x07060302u);
            pq.z = __builtin_amdgcn_perm(w5, w4, 0x07060302u);
            pq.w = __builtin_amdgcn_perm(w7, w6, 0x07060302u);
            bf16x8 af = __builtin_bit_cast(bf16x8, pq);
            if (u == 3) mcur = mnext;
            __syncthreads();                       // drains only iter-old loads (~free)
            __builtin_amdgcn_sched_barrier(0);     // pin: loads below stay below
            // ---- prefetch tile k+2 into freed slot cb ----
            if (k < 62) {
                pv[cb][0] = *(const bf16x8*)(Vg0 + (k + 2) * 64);
                pv[cb][1] = *(const bf16x8*)(Vg1 + (k + 2) * 64);
                pBD[cb][0] = *(const float4*)(Bp + (k + 2) * 64);
                pBD[cb][1] = *(const float4*)(Bp + (k + 2) * 64 + 4);
                pBD[cb][2] = *(const float4*)(Dp + (k + 2) * 64);
                pBD[cb][3] = *(const float4*)(Dp + (k + 2) * 64 + 4);
            }
            if (u == 0 && t < 15) mnext = *(const unsigned*)(mp + (t + 1) * 4);
            // ---- MFMA tile k: af (regs) x Vb[cb] ----
#pragma unroll
            for (int nt = 0; nt < 4; nt++) {
                bf16x8 bv = *(const bf16x8*)&Vb[cb][whead * 64 + nt * 16 + nn][jhalf * 32 + quad * 8];
                acc[nt] = __builtin_amdgcn_mfma_f32_16x16x32_bf16(af, bv, acc[nt], 0, 0, 0);
            }
            accd = __builtin_amdgcn_mfma_f32_16x16x32_bf16(af, onef, accd, 0, 0, 0);
        }
    }
    // denominator partials: C-layout row = quad*4+rr (any col; use nn==0 lanes)
    if (nn == 0) {
#pragma unroll
        for (int rr = 0; rr < 4; rr++)
            denomp[jhalf][whead][strip * 16 + quad * 4 + rr] = accd[rr];
    }
    __syncthreads();   // denomp visible; all Vb reads of k=63 done
    // combine jhalf partials via cmb overlay on Vb[0] slab
    float (*cmb)[64][8] = reinterpret_cast<float (*)[64][8]>(&Vb[0][0][0]);
    if (jhalf == 1) {
        *(f32x4*)&cmb[ws][lane][0] = acc[0];
        *(f32x4*)&cmb[ws][lane][4] = acc[1];
    }
    __syncthreads();
    if (jhalf == 0) {
        f32x4 o0 = acc[0] + *(const f32x4*)&cmb[ws][lane][0];
        f32x4 o1 = acc[1] + *(const f32x4*)&cmb[ws][lane][4];
#pragma unroll
        for (int rr = 0; rr < 4; rr++) {
            int il = strip * 16 + quad * 4 + rr;
            float dnm = fmaxf(denomp[0][whead][il] + denomp[1][whead][il], 1e-30f);
            float v0 = o0[rr] / dnm;
            float v1 = o1[rr] / dnm;
            v0 = v0 > 0.f ? v0 : __expf(v0) - 1.f;
            v1 = v1 > 0.f ? v1 : __expf(v1) - 1.f;
            unsigned oi = (unsigned)(i0 + il) * 512 + hb * 128 + whead * 64 + nn;
            out[oi] = v0;
            out[oi + 16] = v1;
        }
    }
    __syncthreads();
    if (jhalf == 1) {
        *(f32x4*)&cmb[ws][lane][0] = acc[2];
        *(f32x4*)&cmb[ws][lane][4] = acc[3];
    }
    __syncthreads();
    if (jhalf == 0) {
        f32x4 o0 = acc[2] + *(const f32x4*)&cmb[ws][lane][0];
        f32x4 o1 = acc[3] + *(const f32x4*)&cmb[ws][lane][4];
#pragma unroll
        for (int rr = 0; rr < 4; rr++) {
            int il = strip * 16 + quad * 4 + rr;
            float dnm = fmaxf(denomp[0][whead][il] + denomp[1][whead][il], 1e-30f);
            float v0 = o0[rr] / dnm;
            float v1 = o1[rr] / dnm;
            v0 = v0 > 0.f ? v0 : __expf(v0) - 1.f;
            v1 = v1 > 0.f ? v1 : __expf(v1) - 1.f;
            unsigned oi = (unsigned)(i0 + il) * 512 + hb * 128 + whead * 64 + 32 + nn;
            out[oi] = v0;
            out[oi + 16] = v1;
        }
    }
}

extern "C" void kernel_launch(void* const* d_in, const int* in_sizes, int n_in,
                              void* d_out, int out_size, void* d_ws, size_t ws_size,
                              hipStream_t stream) {
    const float* h   = (const float*)d_in[0];   // 4096 x 512 fp32
    const int*   adj = (const int*)d_in[1];     // 4096 x 4096 int32
    const float* W   = (const float*)d_in[2];   // 512 x 512 fp32
    const float* a   = (const float*)d_in[3];   // 128 fp32

    char* ws = (char*)d_ws;
    ushort_t* WhT = (ushort_t*)ws;                           // 4 MB
    ushort_t* WT  = (ushort_t*)(ws + (4u << 20));            // 512 KB
    float* expA = (float*)(ws + (4u << 20) + (512u << 10));  // 4 x 128 KB
    float* expC = expA + 8 * 4096;
    float* expB = expC + 8 * 4096;
    float* expD = expB + 8 * 4096;
    unsigned char* pkm = (unsigned char*)(ws + (5u << 20));  // 2 MB bitmask

    pack_adj<<<1024, 256, 0, stream>>>(adj, pkm);
    transpose_w<<<256, 256, 0, stream>>>(W, WT);
    gemm_whT<<<512, 256, 0, stream>>>(WT, h, a, WhT, expA, expC, expB, expD);
    gat_attn<<<512, 512, 0, stream>>>(pkm, WhT, expA, expC, expB, expD,
                                      (float*)d_out);
}

// Round 13
// 168.778 us; speedup vs baseline: 1.0552x; 1.0552x over previous
//
#include <hip/hip_runtime.h>
#include <hip/hip_bf16.h>

// fp32 inputs (confirmed r2). Internal pipeline bf16 MFMA.
// Gen identity: w = exp2(max(e,0.2e)) = max(A_i*B_j, C_i*D_j).
// r13 = j-tile 128 attn (32 barriers, each B-frag LDS read feeds 2 MFMAs,
//   thread generates BOTH strip A-fragments sharing B/D/mask loads) +
//   pack_adj fused into the gemm launch (independent blocks, overlap).
// Mask layout: byte pk[i*512 + g*32 + kb] bits r for j = kb*128 + (g>>2)*32 + (g&3)*8 + r.

typedef unsigned short ushort_t;
typedef __attribute__((ext_vector_type(8))) short bf16x8;
typedef __attribute__((ext_vector_type(4))) float f32x4;

#define LOG2E 1.4426950408889634f

__device__ __forceinline__ ushort_t f2bf(float x) {
    unsigned u = __builtin_bit_cast(unsigned, x);
    u += 0x7FFFu + ((u >> 16) & 1u);   // RNE
    return (ushort_t)(u >> 16);
}

// ---------------- kernel 1: WT[c][k] = W[k][c], 512x512, fp32 -> bf16 ----------------
__global__ __launch_bounds__(256) void transpose_w(const float* __restrict__ W,
                                                   ushort_t* __restrict__ WT) {
    __shared__ ushort_t t[32][33];
    int bx = blockIdx.x & 15, by = blockIdx.x >> 4;
    int tx = threadIdx.x & 31, ty = threadIdx.x >> 5;
#pragma unroll
    for (int i = 0; i < 32; i += 8)
        t[ty + i][tx] = f2bf(W[(by * 32 + ty + i) * 512 + bx * 32 + tx]);
    __syncthreads();
#pragma unroll
    for (int i = 0; i < 32; i += 8)
        WT[(bx * 32 + ty + i) * 512 + by * 32 + tx] = t[tx][ty + i];
}

// -------- kernel 2 (fused): blocks 0-511 = gemm (r8 proven body); 512-1535 = pack ----
__global__ __launch_bounds__(256, 4) void gemm_pack(const ushort_t* __restrict__ WT,
                                                    const float* __restrict__ h,
                                                    const float* __restrict__ a,
                                                    ushort_t* __restrict__ WhT,
                                                    float* __restrict__ expA,
                                                    float* __restrict__ expC,
                                                    float* __restrict__ expB,
                                                    float* __restrict__ expD,
                                                    const int* __restrict__ adj,
                                                    unsigned char* __restrict__ pk) {
    __shared__ __align__(16) ushort_t Al[2][64][72];
    __shared__ __align__(16) ushort_t Bl[2][64][72];
    __shared__ float asrc[64], adst[64];
    __shared__ float sred[2][4][64];
    int tid = threadIdx.x;
    if (blockIdx.x >= 512) {
        // ---------------- pack branch ----------------
        int pbid = blockIdx.x - 512;
        int wv = tid >> 6, lane = tid & 63;
        int row = pbid * 4 + wv;
        const int* ap = adj + (unsigned)row * 4096 + lane;
        unsigned char* pp = pk + (unsigned)row * 512;
        int g = lane;                                 // lanes 0..15 write
        int sv = ((g >> 2) & 1) * 4 + (g & 3);
        int cpar = g >> 3;
#pragma unroll 2
        for (int t = 0; t < 8; t++) {
            unsigned long long m[8];
#pragma unroll
            for (int c8 = 0; c8 < 8; c8++)
                m[c8] = __ballot(ap[(t * 8 + c8) * 64] > 0);
            if (lane < 16) {
                unsigned w = 0;
#pragma unroll
                for (int kq = 0; kq < 4; kq++) {
                    unsigned b = (unsigned)(m[2 * kq + cpar] >> (8 * sv)) & 0xFFu;
                    w |= b << (8 * kq);
                }
                *(unsigned*)(pp + g * 32 + t * 4) = w;
            }
        }
        return;
    }
    // ---------------- gemm branch (r8/r12 proven) ----------------
    int wave = tid >> 6, lane = tid & 63, quad = lane >> 4, nn = lane & 15;
    int mb = blockIdx.x & 7, nb = blockIdx.x >> 3;
    if (tid < 64) {
        asrc[tid] = a[tid] * LOG2E;
        adst[tid] = a[64 + tid] * LOG2E;
    }
    int r = tid >> 2, s0 = tid & 3;
    const ushort_t* Ag = WT + (unsigned)((mb * 64 + r) * 512 + s0 * 8);
    const float* Bg = h + (unsigned)((nb * 64 + r) * 512 + s0 * 8);
    bf16x8 pA0 = *(const bf16x8*)(Ag);
    bf16x8 pA1 = *(const bf16x8*)(Ag + 32);
    float4 pb0 = *(const float4*)(Bg);
    float4 pb1 = *(const float4*)(Bg + 4);
    float4 pb2 = *(const float4*)(Bg + 32);
    float4 pb3 = *(const float4*)(Bg + 36);
    f32x4 acc[4] = {};
#pragma unroll 2
    for (int t = 0; t < 8; t++) {
        int cb = t & 1;
        *(bf16x8*)&Al[cb][r][s0 * 8] = pA0;
        *(bf16x8*)&Al[cb][r][s0 * 8 + 32] = pA1;
        bf16x8 bv;
        bv[0] = (short)f2bf(pb0.x); bv[1] = (short)f2bf(pb0.y);
        bv[2] = (short)f2bf(pb0.z); bv[3] = (short)f2bf(pb0.w);
        bv[4] = (short)f2bf(pb1.x); bv[5] = (short)f2bf(pb1.y);
        bv[6] = (short)f2bf(pb1.z); bv[7] = (short)f2bf(pb1.w);
        *(bf16x8*)&Bl[cb][r][s0 * 8] = bv;
        bv[0] = (short)f2bf(pb2.x); bv[1] = (short)f2bf(pb2.y);
        bv[2] = (short)f2bf(pb2.z); bv[3] = (short)f2bf(pb2.w);
        bv[4] = (short)f2bf(pb3.x); bv[5] = (short)f2bf(pb3.y);
        bv[6] = (short)f2bf(pb3.z); bv[7] = (short)f2bf(pb3.w);
        *(bf16x8*)&Bl[cb][r][s0 * 8 + 32] = bv;
        if (t < 7) {
            int ko = (t + 1) * 64;
            pA0 = *(const bf16x8*)(Ag + ko);
            pA1 = *(const bf16x8*)(Ag + ko + 32);
            pb0 = *(const float4*)(Bg + ko);
            pb1 = *(const float4*)(Bg + ko + 4);
            pb2 = *(const float4*)(Bg + ko + 32);
            pb3 = *(const float4*)(Bg + ko + 36);
        }
        if (t > 0) {
            int pb = cb ^ 1;
            bf16x8 af0 = *(const bf16x8*)&Al[pb][wave * 16 + nn][quad * 8];
            bf16x8 af1 = *(const bf16x8*)&Al[pb][wave * 16 + nn][32 + quad * 8];
#pragma unroll
            for (int nt = 0; nt < 4; nt++) {
                bf16x8 b0 = *(const bf16x8*)&Bl[pb][nt * 16 + nn][quad * 8];
                bf16x8 b1 = *(const bf16x8*)&Bl[pb][nt * 16 + nn][32 + quad * 8];
                acc[nt] = __builtin_amdgcn_mfma_f32_16x16x32_bf16(af0, b0, acc[nt], 0, 0, 0);
                acc[nt] = __builtin_amdgcn_mfma_f32_16x16x32_bf16(af1, b1, acc[nt], 0, 0, 0);
            }
        }
        __syncthreads();
    }
    {
        bf16x8 af0 = *(const bf16x8*)&Al[1][wave * 16 + nn][quad * 8];
        bf16x8 af1 = *(const bf16x8*)&Al[1][wave * 16 + nn][32 + quad * 8];
#pragma unroll
        for (int nt = 0; nt < 4; nt++) {
            bf16x8 b0 = *(const bf16x8*)&Bl[1][nt * 16 + nn][quad * 8];
            bf16x8 b1 = *(const bf16x8*)&Bl[1][nt * 16 + nn][32 + quad * 8];
            acc[nt] = __builtin_amdgcn_mfma_f32_16x16x32_bf16(af0, b0, acc[nt], 0, 0, 0);
            acc[nt] = __builtin_amdgcn_mfma_f32_16x16x32_bf16(af1, b1, acc[nt], 0, 0, 0);
        }
    }
    int row0 = mb * 64 + wave * 16 + quad * 4;
    int col0 = nb * 64 + nn;
    int f0i = wave * 16 + quad * 4;
#pragma unroll
    for (int nt = 0; nt < 4; nt++) {
        float s = 0.f, d = 0.f;
#pragma unroll
        for (int rr = 0; rr < 4; rr++) {
            float v = acc[nt][rr];
            WhT[(unsigned)((row0 + rr) * 4096 + col0 + nt * 16)] = f2bf(v);
            s += v * asrc[f0i + rr];
            d += v * adst[f0i + rr];
        }
        s += __shfl_xor(s, 16); s += __shfl_xor(s, 32);
        d += __shfl_xor(d, 16); d += __shfl_xor(d, 32);
        if (quad == 0) { sred[0][wave][nt * 16 + nn] = s; sred[1][wave][nt * 16 + nn] = d; }
    }
    __syncthreads();
    if (tid < 64) {
        float s = sred[0][0][tid] + sred[0][1][tid] + sred[0][2][tid] + sred[0][3][tid];
        unsigned idx = mb * 4096 + nb * 64 + tid;
        expA[idx] = __builtin_amdgcn_exp2f(s);
        expC[idx] = __builtin_amdgcn_exp2f(0.2f * s);
    } else if (tid < 128) {
        int c = tid - 64;
        float d = sred[1][0][c] + sred[1][1][c] + sred[1][2][c] + sred[1][3][c];
        unsigned idx = mb * 4096 + nb * 64 + c;
        expB[idx] = __builtin_amdgcn_exp2f(d);
        expD[idx] = __builtin_amdgcn_exp2f(0.2f * d);
    }
}

// -------- kernel 3: fused attention, j-tile 128, identity mapping, 2 strips/thread ---
// 512 blocks x 512 thr (512,4). wave=(whead, jq); thread gen = A-frags for rows
// nn and 16+nn over j = kb*128 + jq*32 + quad*8 + 0..7. 32 iters, 1 barrier each.
// Each B-frag LDS read feeds 2 MFMAs (both strips). Denominator via P@ones MFMA.
__global__ __launch_bounds__(512, 4) void gat_attn(const unsigned char* __restrict__ pk,
                                                   const ushort_t* __restrict__ WhT,
                                                   const float* __restrict__ expA,
                                                   const float* __restrict__ expC,
                                                   const float* __restrict__ expB,
                                                   const float* __restrict__ expD,
                                                   float* __restrict__ out) {
    __shared__ __align__(16) ushort_t Vb[2][128][136];   // 69632 B (cmb overlays)
    __shared__ float denomp[4][2][32];
    int tid = threadIdx.x;
    int wave = tid >> 6, lane = tid & 63, quad = lane >> 4, nn = lane & 15;
    int hb = blockIdx.x >> 7, ib = blockIdx.x & 127;   // adj row-band on one XCD
    int i0 = ib * 32;
    int whead = wave & 1, jq = wave >> 1;              // jq 0..3
    int g = jq * 4 + quad;
    int head = hb * 2 + whead;
    float Ai0 = expA[head * 4096 + i0 + nn];
    float Ci0 = expC[head * 4096 + i0 + nn];
    float Ai1 = expA[head * 4096 + i0 + 16 + nn];
    float Ci1 = expC[head * 4096 + i0 + 16 + nn];
    const unsigned char* mpA = pk + (unsigned)(i0 + nn) * 512 + g * 32;
    const unsigned char* mpB = mpA + 16 * 512;
    const float* Bp = expB + (unsigned)head * 4096 + jq * 32 + quad * 8;
    const float* Dp = expD + (unsigned)head * 4096 + jq * 32 + quad * 8;
    // V staging: row vrow, 4 x 16B segs at cols vs*8 + s*32
    int vrow = tid >> 2, vs = tid & 3;
    const ushort_t* Vg = WhT + (unsigned)(hb * 128 + vrow) * 4096 + vs * 8;
    bf16x8 onef;
#pragma unroll
    for (int i = 0; i < 8; i++) onef[i] = (short)0x3F80;   // bf16 1.0
    f32x4 acc[2][4] = {};
    f32x4 accd[2] = {};
    bf16x8 pv[4];
    float4 pBD[4];
    pv[0] = *(const bf16x8*)(Vg);
    pv[1] = *(const bf16x8*)(Vg + 32);
    pv[2] = *(const bf16x8*)(Vg + 64);
    pv[3] = *(const bf16x8*)(Vg + 96);
    pBD[0] = *(const float4*)(Bp);
    pBD[1] = *(const float4*)(Bp + 4);
    pBD[2] = *(const float4*)(Dp);
    pBD[3] = *(const float4*)(Dp + 4);
    unsigned mcA = *(const unsigned*)(mpA);
    unsigned mcB = *(const unsigned*)(mpB);
    unsigned mnA = 0, mnB = 0;
    for (int t = 0; t < 8; t++) {
#pragma unroll
        for (int u = 0; u < 4; u++) {
            int kb = t * 4 + u;
            int cb = kb & 1;
            // ---- store V tile kb ----
            *(bf16x8*)&Vb[cb][vrow][vs * 8] = pv[0];
            *(bf16x8*)&Vb[cb][vrow][vs * 8 + 32] = pv[1];
            *(bf16x8*)&Vb[cb][vrow][vs * 8 + 64] = pv[2];
            *(bf16x8*)&Vb[cb][vrow][vs * 8 + 96] = pv[3];
            // ---- gen both strips (shared B/D) ----
            float4 Bv0 = pBD[0], Bv1 = pBD[1], Dv0 = pBD[2], Dv1 = pBD[3];
            bf16x8 af0, af1;
            {
                unsigned w0, w1, w2, w3, w4, w5, w6, w7;
                float w;
                w = fmaxf(Ai0 * Bv0.x, Ci0 * Dv0.x);
                w0 = __builtin_bit_cast(unsigned, w) & 0xFFFF0000u;
                w0 &= (unsigned)__builtin_amdgcn_sbfe(mcA, u * 8 + 0, 1);
                w = fmaxf(Ai0 * Bv0.y, Ci0 * Dv0.y);
                w1 = __builtin_bit_cast(unsigned, w) & 0xFFFF0000u;
                w1 &= (unsigned)__builtin_amdgcn_sbfe(mcA, u * 8 + 1, 1);
                w = fmaxf(Ai0 * Bv0.z, Ci0 * Dv0.z);
                w2 = __builtin_bit_cast(unsigned, w) & 0xFFFF0000u;
                w2 &= (unsigned)__builtin_amdgcn_sbfe(mcA, u * 8 + 2, 1);
                w = fmaxf(Ai0 * Bv0.w, Ci0 * Dv0.w);
                w3 = __builtin_bit_cast(unsigned, w) & 0xFFFF0000u;
                w3 &= (unsigned)__builtin_amdgcn_sbfe(mcA, u * 8 + 3, 1);
                w = fmaxf(Ai0 * Bv1.x, Ci0 * Dv1.x);
                w4 = __builtin_bit_cast(unsigned, w) & 0xFFFF0000u;
                w4 &= (unsigned)__builtin_amdgcn_sbfe(mcA, u * 8 + 4, 1);
                w = fmaxf(Ai0 * Bv1.y, Ci0 * Dv1.y);
                w5 = __builtin_bit_cast(unsigned, w) & 0xFFFF0000u;
                w5 &= (unsigned)__builtin_amdgcn_sbfe(mcA, u * 8 + 5, 1);
                w = fmaxf(Ai0 * Bv1.z, Ci0 * Dv1.z);
                w6 = __builtin_bit_cast(unsigned, w) & 0xFFFF0000u;
                w6 &= (unsigned)__builtin_amdgcn_sbfe(mcA, u * 8 + 6, 1);
                w = fmaxf(Ai0 * Bv1.w, Ci0 * Dv1.w);
                w7 = __builtin_bit_cast(unsigned, w) & 0xFFFF0000u;
                w7 &= (unsigned)__builtin_amdgcn_sbfe(mcA, u * 8 + 7, 1);
                uint4 pq;
                pq.x = __builtin_amdgcn_perm(w1, w0, 0x07060302u);
                pq.y = __builtin_amdgcn_perm(w3, w2, 0x07060302u);
                pq.z = __builtin_amdgcn_perm(w5, w4, 0x07060302u);
                pq.w = __builtin_amdgcn_perm(w7, w6, 0x07060302u);
                af0 = __builtin_bit_cast(bf16x8, pq);
                w = fmaxf(Ai1 * Bv0.x, Ci1 * Dv0.x);
                w0 = __builtin_bit_cast(unsigned, w) & 0xFFFF0000u;
                w0 &= (unsigned)__builtin_amdgcn_sbfe(mcB, u * 8 + 0, 1);
                w = fmaxf(Ai1 * Bv0.y, Ci1 * Dv0.y);
                w1 = __builtin_bit_cast(unsigned, w) & 0xFFFF0000u;
                w1 &= (unsigned)__builtin_amdgcn_sbfe(mcB, u * 8 + 1, 1);
                w = fmaxf(Ai1 * Bv0.z, Ci1 * Dv0.z);
                w2 = __builtin_bit_cast(unsigned, w) & 0xFFFF0000u;
                w2 &= (unsigned)__builtin_amdgcn_sbfe(mcB, u * 8 + 2, 1);
                w = fmaxf(Ai1 * Bv0.w, Ci1 * Dv0.w);
                w3 = __builtin_bit_cast(unsigned, w) & 0xFFFF0000u;
                w3 &= (unsigned)__builtin_amdgcn_sbfe(mcB, u * 8 + 3, 1);
                w = fmaxf(Ai1 * Bv1.x, Ci1 * Dv1.x);
                w4 = __builtin_bit_cast(unsigned, w) & 0xFFFF0000u;
                w4 &= (unsigned)__builtin_amdgcn_sbfe(mcB, u * 8 + 4, 1);
                w = fmaxf(Ai1 * Bv1.y, Ci1 * Dv1.y);
                w5 = __builtin_bit_cast(unsigned, w) & 0xFFFF0000u;
                w5 &= (unsigned)__builtin_amdgcn_sbfe(mcB, u * 8 + 5, 1);
                w = fmaxf(Ai1 * Bv1.z, Ci1 * Dv1.z);
                w6 = __builtin_bit_cast(unsigned, w) & 0xFFFF0000u;
                w6 &= (unsigned)__builtin_amdgcn_sbfe(mcB, u * 8 + 6, 1);
                w = fmaxf(Ai1 * Bv1.w, Ci1 * Dv1.w);
                w7 = __builtin_bit_cast(unsigned, w) & 0xFFFF0000u;
                w7 &= (unsigned)__builtin_amdgcn_sbfe(mcB, u * 8 + 7, 1);
                pq.x = __builtin_amdgcn_perm(w1, w0, 0x07060302u);
                pq.y = __builtin_amdgcn_perm(w3, w2, 0x07060302u);
                pq.z = __builtin_amdgcn_perm(w5, w4, 0x07060302u);
                pq.w = __builtin_amdgcn_perm(w7, w6, 0x07060302u);
                af1 = __builtin_bit_cast(bf16x8, pq);
            }
            if (u == 3) { mcA = mnA; mcB = mnB; }
            __syncthreads();                       // drains only iter-old loads
            __builtin_amdgcn_sched_barrier(0);     // pin: loads below stay below
            // ---- prefetch tile kb+1 ----
            if (kb < 31) {
                const ushort_t* vp = Vg + (kb + 1) * 128;
                pv[0] = *(const bf16x8*)(vp);
                pv[1] = *(const bf16x8*)(vp + 32);
                pv[2] = *(const bf16x8*)(vp + 64);
                pv[3] = *(const bf16x8*)(vp + 96);
                pBD[0] = *(const float4*)(Bp + (kb + 1) * 128);
                pBD[1] = *(const float4*)(Bp + (kb + 1) * 128 + 4);
                pBD[2] = *(const float4*)(Dp + (kb + 1) * 128);
                pBD[3] = *(const float4*)(Dp + (kb + 1) * 128 + 4);
            }
            if (u == 0 && t < 7) {
                mnA = *(const unsigned*)(mpA + (t + 1) * 4);
                mnB = *(const unsigned*)(mpB + (t + 1) * 4);
            }
            // ---- MFMA tile kb: each bv feeds both strips ----
#pragma unroll
            for (int nt = 0; nt < 4; nt++) {
                bf16x8 bv = *(const bf16x8*)&Vb[cb][whead * 64 + nt * 16 + nn][jq * 32 + quad * 8];
                acc[0][nt] = __builtin_amdgcn_mfma_f32_16x16x32_bf16(af0, bv, acc[0][nt], 0, 0, 0);
                acc[1][nt] = __builtin_amdgcn_mfma_f32_16x16x32_bf16(af1, bv, acc[1][nt], 0, 0, 0);
            }
            accd[0] = __builtin_amdgcn_mfma_f32_16x16x32_bf16(af0, onef, accd[0], 0, 0, 0);
            accd[1] = __builtin_amdgcn_mfma_f32_16x16x32_bf16(af1, onef, accd[1], 0, 0, 0);
        }
    }
    __syncthreads();   // all Vb reads of tile 31 done before cmb overlay writes
    // denominator partials: row = s*16 + quad*4 + rr
    if (nn == 0) {
#pragma unroll
        for (int s = 0; s < 2; s++)
#pragma unroll
            for (int rr = 0; rr < 4; rr++)
                denomp[jq][whead][s * 16 + quad * 4 + rr] = accd[s][rr];
    }
    // combine jq partials via cmb overlay on Vb
    float (*cmb)[3][64][32] = reinterpret_cast<float (*)[3][64][32]>(&Vb[0][0][0]);
    if (jq > 0) {
#pragma unroll
        for (int s = 0; s < 2; s++)
#pragma unroll
            for (int nt = 0; nt < 4; nt++)
                *(f32x4*)&cmb[whead][jq - 1][lane][s * 16 + nt * 4] = acc[s][nt];
    }
    __syncthreads();
    if (jq == 0) {
#pragma unroll
        for (int s = 0; s < 2; s++) {
#pragma unroll
            for (int nt = 0; nt < 4; nt++) {
                f32x4 o = acc[s][nt]
                        + *(const f32x4*)&cmb[whead][0][lane][s * 16 + nt * 4]
                        + *(const f32x4*)&cmb[whead][1][lane][s * 16 + nt * 4]
                        + *(const f32x4*)&cmb[whead][2][lane][s * 16 + nt * 4];
#pragma unroll
                for (int rr = 0; rr < 4; rr++) {
                    int il = s * 16 + quad * 4 + rr;
                    float dnm = fmaxf(denomp[0][whead][il] + denomp[1][whead][il]
                                    + denomp[2][whead][il] + denomp[3][whead][il], 1e-30f);
                    float v = o[rr] / dnm;
                    v = v > 0.f ? v : __expf(v) - 1.f;
                    out[(unsigned)(i0 + il) * 512 + hb * 128 + whead * 64 + nt * 16 + nn] = v;
                }
            }
        }
    }
}

extern "C" void kernel_launch(void* const* d_in, const int* in_sizes, int n_in,
                              void* d_out, int out_size, void* d_ws, size_t ws_size,
                              hipStream_t stream) {
    const float* h   = (const float*)d_in[0];   // 4096 x 512 fp32
    const int*   adj = (const int*)d_in[1];     // 4096 x 4096 int32
    const float* W   = (const float*)d_in[2];   // 512 x 512 fp32
    const float* a   = (const float*)d_in[3];   // 128 fp32

    char* ws = (char*)d_ws;
    ushort_t* WhT = (ushort_t*)ws;                           // 4 MB
    ushort_t* WT  = (ushort_t*)(ws + (4u << 20));            // 512 KB
    float* expA = (float*)(ws + (4u << 20) + (512u << 10));  // 4 x 128 KB
    float* expC = expA + 8 * 4096;
    float* expB = expC + 8 * 4096;
    float* expD = expB + 8 * 4096;
    unsigned char* pkm = (unsigned char*)(ws + (5u << 20));  // 2 MB bitmask

    transpose_w<<<256, 256, 0, stream>>>(W, WT);
    gemm_pack<<<1536, 256, 0, stream>>>(WT, h, a, WhT, expA, expC, expB, expD,
                                        adj, pkm);
    gat_attn<<<512, 512, 0, stream>>>(pkm, WhT, expA, expC, expB, expD,
                                      (float*)d_out);
}